// Round 2
// baseline (177.773 us; speedup 1.0000x reference)
//
#include <hip/hip_runtime.h>

// out[b][j] = x[b][(j - s_b) mod T]
//
// LDS-realign version: each block handles CHUNK=1024 consecutive output floats
// of one row. The source range [chunk0-s, chunk0-s+nOut) is loaded with
// 16B-ALIGNED float4 loads (rounded down to a 4-float boundary), staged in LDS
// with a +1-float-per-4 padded layout (bank-conflict-free: address stride 5
// mod 32 => exact 2-way aliasing, free), then read back misaligned and stored
// with 16B-aligned float4 stores. 2 VMEM instructions per thread instead of 5.

#define CHUNK 1024  // floats per block = 256 threads * 4

__device__ __forceinline__ int pad(int i) { return i + (i >> 2); }

__global__ __launch_bounds__(256) void roll_rows_lds(
    const float* __restrict__ x,
    const int* __restrict__ shifts,
    float* __restrict__ out,
    int T) {
    __shared__ float lds[CHUNK + 4 + ((CHUNK + 4) >> 2) + 4];  // padded staging

    const int b = blockIdx.y;
    const int chunk0 = blockIdx.x * CHUNK;   // first output column of block
    const int t = threadIdx.x;

    int s = shifts[b] % T;
    if (s < 0) s += T;

    const int nOut = min(CHUNK, T - chunk0);       // floats this block writes (mult of 4)
    const int base = chunk0 - s;                    // first source float needed
    const int off = ((base % 4) + 4) % 4;           // misalignment within float4
    const int baseAl = base - off;                  // aligned load start (mult of 4)
    const int nV = (nOut + off + 3) >> 2;           // aligned float4s to stage

    const float* __restrict__ xr = x + (size_t)b * (size_t)T;

    // ---- stage: aligned float4 global loads -> padded LDS (b32 writes) ----
    for (int k = t; k < nV; k += 256) {
        int src = baseAl + 4 * k;
        if (src < 0) src += T;
        else if (src >= T) src -= T;               // stays 16B-aligned (T % 4 == 0)
        const float4 v = *reinterpret_cast<const float4*>(xr + src);
        const int i = 4 * k;
        lds[pad(i + 0)] = v.x;
        lds[pad(i + 1)] = v.y;
        lds[pad(i + 2)] = v.z;
        lds[pad(i + 3)] = v.w;
    }
    __syncthreads();

    // ---- realign: padded LDS reads -> aligned float4 global store ----
    const int j = 4 * t;                            // output offset within chunk
    if (j < nOut) {
        const int i = off + j;                      // staged index of first float
        float4 o;
        o.x = lds[pad(i + 0)];
        o.y = lds[pad(i + 1)];
        o.z = lds[pad(i + 2)];
        o.w = lds[pad(i + 3)];
        *reinterpret_cast<float4*>(out + (size_t)b * (size_t)T + chunk0 + j) = o;
    }
}

// Generic scalar fallback (T not divisible by 4).
__global__ void roll_rows_scalar(const float* __restrict__ x,
                                 const int* __restrict__ shifts,
                                 float* __restrict__ out,
                                 int T) {
    const int b = blockIdx.y;
    const int j = blockIdx.x * blockDim.x + threadIdx.x;
    if (j >= T) return;
    int s = shifts[b] % T;
    if (s < 0) s += T;
    int i = j - s;
    if (i < 0) i += T;
    out[(size_t)b * T + j] = x[(size_t)b * T + i];
}

extern "C" void kernel_launch(void* const* d_in, const int* in_sizes, int n_in,
                              void* d_out, int out_size, void* d_ws, size_t ws_size,
                              hipStream_t stream) {
    const float* x = (const float*)d_in[0];
    const int* shifts = (const int*)d_in[1];
    float* out = (float*)d_out;

    const int B = in_sizes[1];
    const int T = in_sizes[0] / B;

    if ((T & 3) == 0) {
        dim3 block(256);
        dim3 grid((T + CHUNK - 1) / CHUNK, B);
        roll_rows_lds<<<grid, block, 0, stream>>>(x, shifts, out, T);
    } else {
        dim3 block(256);
        dim3 grid((T + 255) / 256, B);
        roll_rows_scalar<<<grid, block, 0, stream>>>(x, shifts, out, T);
    }
}